// Round 4
// baseline (100.782 us; speedup 1.0000x reference)
//
#include <hip/hip_runtime.h>

// Problem constants (B=1 throughout)
constexpr int kH  = 1024;
constexpr int kS  = 48;
constexpr int kNH = 32;
constexpr int kDH = 32;
constexpr float kSF = 0.2f;
// Output: [48, 48*32*32*32] f32. Row x = O[x] (32x32 = 1024 f32) tiled 1536 times.
constexpr int kRepsPerRow = kS * kNH;          // 1536
constexpr int kRowF4      = kRepsPerRow * 256; // 393216 float4 per output row

__device__ __forceinline__ float4 ld4(const float* p) {
    return *reinterpret_cast<const float4*>(p);
}
__device__ __forceinline__ void st4(float* p, float4 v) {
    *reinterpret_cast<float4*>(p) = v;
}
__device__ __forceinline__ float dot4(float4 a, float4 b) {
    return a.x * b.x + a.y * b.y + a.z * b.z + a.w * b.w;
}

// ---------------------------------------------------------------------------
// Kernel 1: projections, register-tiled, no LDS, perfectly balanced.
// 768 blocks x 256 threads = 3072 waves = 3 g x 4 s-quarters(12) x 256 o-quads.
// Lanes split K 64-way: lane l covers k = p*256 + l*4 .. +3, p=0..3.
// Per pass: load 4 W float4 (o-quad, register-reused across 12 s), then for
// each s: one X float4 -> 4 dot4. 1 global b128 read per 4 FMA, X is
// L2-resident (147 MB total L2 traffic ~4.3 us), W streamed once (12.6 MB).
// 48 accs butterfly-reduced over 64 lanes; lane 0 stores 12 dwordx4 + bias.
// ---------------------------------------------------------------------------
__global__ __launch_bounds__(256) void proj_kernel(
    const float* __restrict__ q, const float* __restrict__ k, const float* __restrict__ v,
    const float* __restrict__ Wq, const float* __restrict__ bq,
    const float* __restrict__ Wk, const float* __restrict__ bk,
    const float* __restrict__ Wv, const float* __restrict__ bv,
    float* __restrict__ ws)
{
    const int w    = blockIdx.x * 4 + (threadIdx.x >> 6); // 0..3071
    const int lane = threadIdx.x & 63;
    const int g    = w >> 10;        // 0=q,1=k,2=v (1024 waves per matrix)
    const int r    = w & 1023;
    const int sq   = r >> 8;         // s-quarter 0..3 (12 rows each)
    const int oq   = r & 255;        // o-quad 0..255
    const int s0   = sq * 12;
    const int o0   = oq * 4;

    const float *X, *W, *Bv;
    if (g == 0)      { X = q; W = Wq; Bv = bq; }
    else if (g == 1) { X = k; W = Wk; Bv = bk; }
    else             { X = v; W = Wv; Bv = bv; }
    float* OUT = ws + g * (kS * kH);

    float acc[4][12];
#pragma unroll
    for (int j = 0; j < 4; ++j)
#pragma unroll
        for (int s = 0; s < 12; ++s) acc[j][s] = 0.f;

#pragma unroll
    for (int p = 0; p < 4; ++p) {
        const int k0 = p * 256 + lane * 4;
        const float4 w0 = ld4(W + (o0 + 0) * kH + k0);
        const float4 w1 = ld4(W + (o0 + 1) * kH + k0);
        const float4 w2 = ld4(W + (o0 + 2) * kH + k0);
        const float4 w3 = ld4(W + (o0 + 3) * kH + k0);
#pragma unroll
        for (int s = 0; s < 12; ++s) {
            const float4 xv = ld4(X + (s0 + s) * kH + k0);
            acc[0][s] += dot4(xv, w0);
            acc[1][s] += dot4(xv, w1);
            acc[2][s] += dot4(xv, w2);
            acc[3][s] += dot4(xv, w3);
        }
    }

#pragma unroll
    for (int j = 0; j < 4; ++j)
#pragma unroll
        for (int s = 0; s < 12; ++s) {
            float a = acc[j][s];
            a += __shfl_xor(a, 1);
            a += __shfl_xor(a, 2);
            a += __shfl_xor(a, 4);
            a += __shfl_xor(a, 8);
            a += __shfl_xor(a, 16);
            a += __shfl_xor(a, 32);
            acc[j][s] = a;
        }

    if (lane == 0) {
        const float4 bb = ld4(Bv + o0);
#pragma unroll
        for (int s = 0; s < 12; ++s) {
            float4 o4;
            o4.x = acc[0][s] + bb.x;
            o4.y = acc[1][s] + bb.y;
            o4.z = acc[2][s] + bb.z;
            o4.w = acc[3][s] + bb.w;
            st4(OUT + (s0 + s) * kH + o0, o4);
        }
    }
}

// ---------------------------------------------------------------------------
// Kernel 2: per-s attention core. One block (256 threads) per s.
//   _sq[n]   = (1/1024) * sum_d qp[s, n*32+d]^2
//   _sk[d,e] = (1/1024) * sum_n kp[s, n*32+d] * qp[s, n*32+e]
//   p[b,c]   = softmax_c( SF * |_sk[c,b] - _sq[b]| )       (stored transposed)
//   O[s,b,d] = sum_c p[b,c] * vp[s, c*32+d]
// ---------------------------------------------------------------------------
__global__ __launch_bounds__(256) void attn_kernel(
    const float* __restrict__ ws, float* __restrict__ O)
{
    const int s = blockIdx.x;
    const int t = threadIdx.x;

    __shared__ float qrow[kH];
    __shared__ float krow[kH];
    __shared__ float vrow[kH];
    __shared__ float sq[kNH];
    __shared__ float sk[kDH][kDH];  // sk[d][e]
    __shared__ float pT[kNH][kNH];  // pT[c][b] = p[b][c]

    const float* qp = ws;
    const float* kp = ws + kS * kH;
    const float* vp = ws + 2 * kS * kH;

    reinterpret_cast<float4*>(qrow)[t] = ld4(qp + s * kH + t * 4);
    reinterpret_cast<float4*>(krow)[t] = ld4(kp + s * kH + t * 4);
    reinterpret_cast<float4*>(vrow)[t] = ld4(vp + s * kH + t * 4);
    __syncthreads();

    if (t < kNH) {
        float a = 0.f;
#pragma unroll
        for (int d = 0; d < kDH; ++d) {
            float x = qrow[t * kDH + d];
            a += x * x;
        }
        sq[t] = a * (1.0f / 1024.0f);
    }
    {
        const int d = t >> 3;
        const int eq = t & 7;
        float4 a = {0.f, 0.f, 0.f, 0.f};
#pragma unroll
        for (int n = 0; n < kNH; ++n) {
            const float kv = krow[n * kDH + d];
            const float4 qv = reinterpret_cast<const float4*>(qrow)[n * 8 + eq];
            a.x += kv * qv.x; a.y += kv * qv.y; a.z += kv * qv.z; a.w += kv * qv.w;
        }
        const float sc = 1.0f / 1024.0f;
        a.x *= sc; a.y *= sc; a.z *= sc; a.w *= sc;
        *reinterpret_cast<float4*>(&sk[d][eq * 4]) = a;
    }
    __syncthreads();

    {
        const int b = t >> 3;
        const int c0 = (t & 7) * 4;
        const float s0 = sq[b];
        float v0 = kSF * fabsf(sk[c0 + 0][b] - s0);
        float v1 = kSF * fabsf(sk[c0 + 1][b] - s0);
        float v2 = kSF * fabsf(sk[c0 + 2][b] - s0);
        float v3 = kSF * fabsf(sk[c0 + 3][b] - s0);
        float m = fmaxf(fmaxf(v0, v1), fmaxf(v2, v3));
        m = fmaxf(m, __shfl_xor(m, 1));
        m = fmaxf(m, __shfl_xor(m, 2));
        m = fmaxf(m, __shfl_xor(m, 4));
        float e0 = __expf(v0 - m);
        float e1 = __expf(v1 - m);
        float e2 = __expf(v2 - m);
        float e3 = __expf(v3 - m);
        float sum = e0 + e1 + e2 + e3;
        sum += __shfl_xor(sum, 1);
        sum += __shfl_xor(sum, 2);
        sum += __shfl_xor(sum, 4);
        const float inv = 1.0f / sum;
        pT[c0 + 0][b] = e0 * inv;
        pT[c0 + 1][b] = e1 * inv;
        pT[c0 + 2][b] = e2 * inv;
        pT[c0 + 3][b] = e3 * inv;
    }
    __syncthreads();

    {
        const int b = t >> 3;
        const int dq = t & 7;
        float4 acc = {0.f, 0.f, 0.f, 0.f};
#pragma unroll
        for (int c = 0; c < kNH; ++c) {
            const float pv = pT[c][b];
            const float4 vv = reinterpret_cast<const float4*>(vrow)[c * 8 + dq];
            acc.x += pv * vv.x; acc.y += pv * vv.y; acc.z += pv * vv.z; acc.w += pv * vv.w;
        }
        reinterpret_cast<float4*>(O + s * kH + b * kDH)[dq] = acc;
    }
}

// ---------------------------------------------------------------------------
// Kernel 3: broadcast. Row x of output = O[x] (1024 f32) tiled 1536 times.
// 1536 blocks = 48 rows x 32 rep-groups of 48. Thread reads one float4 of
// O[x] (L2-hit, O is 192 KB) and issues 48 regular dwordx4 stores — pure
// store stream from cycle ~0, mimicking the 7 TB/s fillBuffer path.
// ---------------------------------------------------------------------------
__global__ __launch_bounds__(256) void bcast_kernel(
    const float* __restrict__ O, float* __restrict__ out)
{
    const int x  = blockIdx.x >> 5;   // output row 0..47
    const int rb = blockIdx.x & 31;   // rep-group 0..31 (48 reps each)
    const int t  = threadIdx.x;

    const float4 v = ld4(O + x * kH + t * 4);
    float4* dst = reinterpret_cast<float4*>(out)
                + (size_t)x * kRowF4 + (size_t)rb * (48 * 256) + t;
#pragma unroll
    for (int i = 0; i < 48; ++i) {
        dst[i * 256] = v;
    }
}

extern "C" void kernel_launch(void* const* d_in, const int* in_sizes, int n_in,
                              void* d_out, int out_size, void* d_ws, size_t ws_size,
                              hipStream_t stream)
{
    (void)in_sizes; (void)n_in; (void)out_size; (void)ws_size;
    const float* q  = (const float*)d_in[0];
    const float* k  = (const float*)d_in[1];
    const float* v  = (const float*)d_in[2];
    const float* Wq = (const float*)d_in[3];
    const float* bq = (const float*)d_in[4];
    const float* Wk = (const float*)d_in[5];
    const float* bk = (const float*)d_in[6];
    const float* Wv = (const float*)d_in[7];
    const float* bv = (const float*)d_in[8];

    float* ws  = (float*)d_ws;                 // qp | kp | vp | O
    float* O   = ws + 3 * kS * kH;
    float* out = (float*)d_out;

    proj_kernel<<<768, 256, 0, stream>>>(q, k, v, Wq, bq, Wk, bk, Wv, bv, ws);
    attn_kernel<<<kS, 256, 0, stream>>>(ws, O);
    bcast_kernel<<<kS * 32, 256, 0, stream>>>(O, out);
}

// Round 5
// 98.623 us; speedup vs baseline: 1.0219x; 1.0219x over previous
//
#include <hip/hip_runtime.h>

// Problem constants (B=1 throughout)
constexpr int kH  = 1024;
constexpr int kS  = 48;
constexpr int kNH = 32;
constexpr int kDH = 32;
constexpr float kSF = 0.2f;
// Output: [48, 48*32*32*32] f32. Row x = O[x] (32x32 = 1024 f32) tiled 1536 times.
constexpr int kRepsPerRow = kS * kNH;          // 1536
constexpr int kRowF4      = kRepsPerRow * 256; // 393216 float4 per output row

typedef float f32x4 __attribute__((ext_vector_type(4)));

__device__ __forceinline__ float4 ld4(const float* p) {
    return *reinterpret_cast<const float4*>(p);
}
__device__ __forceinline__ void st4(float* p, float4 v) {
    *reinterpret_cast<float4*>(p) = v;
}
__device__ __forceinline__ float dot4(float4 a, float4 b) {
    return a.x * b.x + a.y * b.y + a.z * b.z + a.w * b.w;
}

// ---------------------------------------------------------------------------
// Kernel 1: projections, register-tiled, no LDS, perfectly balanced.
// 768 blocks x 256 threads = 3072 waves = 3 g x 4 s-quarters(12) x 256 o-quads.
// Lanes split K 64-way. Per pass: 4 W float4 (register-reused across 12 s),
// then 12 X float4 -> 48 dot4. X is L2-resident (~147 MB L2 traffic),
// W streamed once (12.6 MB). Butterfly-reduce, lane 0 stores dwordx4 + bias.
// ---------------------------------------------------------------------------
__global__ __launch_bounds__(256) void proj_kernel(
    const float* __restrict__ q, const float* __restrict__ k, const float* __restrict__ v,
    const float* __restrict__ Wq, const float* __restrict__ bq,
    const float* __restrict__ Wk, const float* __restrict__ bk,
    const float* __restrict__ Wv, const float* __restrict__ bv,
    float* __restrict__ ws)
{
    const int w    = blockIdx.x * 4 + (threadIdx.x >> 6); // 0..3071
    const int lane = threadIdx.x & 63;
    const int g    = w >> 10;        // 0=q,1=k,2=v (1024 waves per matrix)
    const int r    = w & 1023;
    const int sq   = r >> 8;         // s-quarter 0..3 (12 rows each)
    const int oq   = r & 255;        // o-quad 0..255
    const int s0   = sq * 12;
    const int o0   = oq * 4;

    const float *X, *W, *Bv;
    if (g == 0)      { X = q; W = Wq; Bv = bq; }
    else if (g == 1) { X = k; W = Wk; Bv = bk; }
    else             { X = v; W = Wv; Bv = bv; }
    float* OUT = ws + g * (kS * kH);

    float acc[4][12];
#pragma unroll
    for (int j = 0; j < 4; ++j)
#pragma unroll
        for (int s = 0; s < 12; ++s) acc[j][s] = 0.f;

#pragma unroll
    for (int p = 0; p < 4; ++p) {
        const int k0 = p * 256 + lane * 4;
        const float4 w0 = ld4(W + (o0 + 0) * kH + k0);
        const float4 w1 = ld4(W + (o0 + 1) * kH + k0);
        const float4 w2 = ld4(W + (o0 + 2) * kH + k0);
        const float4 w3 = ld4(W + (o0 + 3) * kH + k0);
#pragma unroll
        for (int s = 0; s < 12; ++s) {
            const float4 xv = ld4(X + (s0 + s) * kH + k0);
            acc[0][s] += dot4(xv, w0);
            acc[1][s] += dot4(xv, w1);
            acc[2][s] += dot4(xv, w2);
            acc[3][s] += dot4(xv, w3);
        }
    }

#pragma unroll
    for (int j = 0; j < 4; ++j)
#pragma unroll
        for (int s = 0; s < 12; ++s) {
            float a = acc[j][s];
            a += __shfl_xor(a, 1);
            a += __shfl_xor(a, 2);
            a += __shfl_xor(a, 4);
            a += __shfl_xor(a, 8);
            a += __shfl_xor(a, 16);
            a += __shfl_xor(a, 32);
            acc[j][s] = a;
        }

    if (lane == 0) {
        const float4 bb = ld4(Bv + o0);
#pragma unroll
        for (int s = 0; s < 12; ++s) {
            float4 o4;
            o4.x = acc[0][s] + bb.x;
            o4.y = acc[1][s] + bb.y;
            o4.z = acc[2][s] + bb.z;
            o4.w = acc[3][s] + bb.w;
            st4(OUT + (s0 + s) * kH + o0, o4);
        }
    }
}

// ---------------------------------------------------------------------------
// Kernel 2: per-s attention core. One block (256 threads) per s.
//   _sq[n]   = (1/1024) * sum_d qp[s, n*32+d]^2
//   _sk[d,e] = (1/1024) * sum_n kp[s, n*32+d] * qp[s, n*32+e]
//   p[b,c]   = softmax_c( SF * |_sk[c,b] - _sq[b]| )       (stored transposed)
//   O[s,b,d] = sum_c p[b,c] * vp[s, c*32+d]
// ---------------------------------------------------------------------------
__global__ __launch_bounds__(256) void attn_kernel(
    const float* __restrict__ ws, float* __restrict__ O)
{
    const int s = blockIdx.x;
    const int t = threadIdx.x;

    __shared__ float qrow[kH];
    __shared__ float krow[kH];
    __shared__ float vrow[kH];
    __shared__ float sq[kNH];
    __shared__ float sk[kDH][kDH];  // sk[d][e]
    __shared__ float pT[kNH][kNH];  // pT[c][b] = p[b][c]

    const float* qp = ws;
    const float* kp = ws + kS * kH;
    const float* vp = ws + 2 * kS * kH;

    reinterpret_cast<float4*>(qrow)[t] = ld4(qp + s * kH + t * 4);
    reinterpret_cast<float4*>(krow)[t] = ld4(kp + s * kH + t * 4);
    reinterpret_cast<float4*>(vrow)[t] = ld4(vp + s * kH + t * 4);
    __syncthreads();

    if (t < kNH) {
        float a = 0.f;
#pragma unroll
        for (int d = 0; d < kDH; ++d) {
            float x = qrow[t * kDH + d];
            a += x * x;
        }
        sq[t] = a * (1.0f / 1024.0f);
    }
    {
        const int d = t >> 3;
        const int eq = t & 7;
        float4 a = {0.f, 0.f, 0.f, 0.f};
#pragma unroll
        for (int n = 0; n < kNH; ++n) {
            const float kv = krow[n * kDH + d];
            const float4 qv = reinterpret_cast<const float4*>(qrow)[n * 8 + eq];
            a.x += kv * qv.x; a.y += kv * qv.y; a.z += kv * qv.z; a.w += kv * qv.w;
        }
        const float sc = 1.0f / 1024.0f;
        a.x *= sc; a.y *= sc; a.z *= sc; a.w *= sc;
        *reinterpret_cast<float4*>(&sk[d][eq * 4]) = a;
    }
    __syncthreads();

    {
        const int b = t >> 3;
        const int c0 = (t & 7) * 4;
        const float s0 = sq[b];
        float v0 = kSF * fabsf(sk[c0 + 0][b] - s0);
        float v1 = kSF * fabsf(sk[c0 + 1][b] - s0);
        float v2 = kSF * fabsf(sk[c0 + 2][b] - s0);
        float v3 = kSF * fabsf(sk[c0 + 3][b] - s0);
        float m = fmaxf(fmaxf(v0, v1), fmaxf(v2, v3));
        m = fmaxf(m, __shfl_xor(m, 1));
        m = fmaxf(m, __shfl_xor(m, 2));
        m = fmaxf(m, __shfl_xor(m, 4));
        float e0 = __expf(v0 - m);
        float e1 = __expf(v1 - m);
        float e2 = __expf(v2 - m);
        float e3 = __expf(v3 - m);
        float sum = e0 + e1 + e2 + e3;
        sum += __shfl_xor(sum, 1);
        sum += __shfl_xor(sum, 2);
        sum += __shfl_xor(sum, 4);
        const float inv = 1.0f / sum;
        pT[c0 + 0][b] = e0 * inv;
        pT[c0 + 1][b] = e1 * inv;
        pT[c0 + 2][b] = e2 * inv;
        pT[c0 + 3][b] = e3 * inv;
    }
    __syncthreads();

    {
        const int b = t >> 3;
        const int dq = t & 7;
        float4 acc = {0.f, 0.f, 0.f, 0.f};
#pragma unroll
        for (int c = 0; c < kNH; ++c) {
            const float pv = pT[c][b];
            const float4 vv = reinterpret_cast<const float4*>(vrow)[c * 8 + dq];
            acc.x += pv * vv.x; acc.y += pv * vv.y; acc.z += pv * vv.z; acc.w += pv * vv.w;
        }
        reinterpret_cast<float4*>(O + s * kH + b * kDH)[dq] = acc;
    }
}

// ---------------------------------------------------------------------------
// Kernel 3: broadcast — round-2's proven config. 4608 blocks = 48 rows x 96
// rep-groups of 16. Thread loads one f32x4 of O[x] (L2-hit) and issues 16
// nontemporal stores (bypass L2 — the streaming-store path that measured
// fastest; regular stores cost ~+20 us on this 302 MB stream).
// ---------------------------------------------------------------------------
__global__ __launch_bounds__(256) void bcast_kernel(
    const float* __restrict__ O, float* __restrict__ out)
{
    const int x  = blockIdx.x / 96;   // output row
    const int rb = blockIdx.x % 96;   // rep-group of 16
    const int t  = threadIdx.x;

    const f32x4 v = *reinterpret_cast<const f32x4*>(O + x * kH + t * 4);
    f32x4* dst = reinterpret_cast<f32x4*>(out)
               + (size_t)x * kRowF4 + (size_t)rb * (16 * 256) + t;
#pragma unroll
    for (int i = 0; i < 16; ++i) {
        __builtin_nontemporal_store(v, dst + i * 256);
    }
}

extern "C" void kernel_launch(void* const* d_in, const int* in_sizes, int n_in,
                              void* d_out, int out_size, void* d_ws, size_t ws_size,
                              hipStream_t stream)
{
    (void)in_sizes; (void)n_in; (void)out_size; (void)ws_size;
    const float* q  = (const float*)d_in[0];
    const float* k  = (const float*)d_in[1];
    const float* v  = (const float*)d_in[2];
    const float* Wq = (const float*)d_in[3];
    const float* bq = (const float*)d_in[4];
    const float* Wk = (const float*)d_in[5];
    const float* bk = (const float*)d_in[6];
    const float* Wv = (const float*)d_in[7];
    const float* bv = (const float*)d_in[8];

    float* ws  = (float*)d_ws;                 // qp | kp | vp | O
    float* O   = ws + 3 * kS * kH;
    float* out = (float*)d_out;

    proj_kernel<<<768, 256, 0, stream>>>(q, k, v, Wq, bq, Wk, bk, Wv, bv, ws);
    attn_kernel<<<kS, 256, 0, stream>>>(ws, O);
    bcast_kernel<<<kS * 96, 256, 0, stream>>>(O, out);
}

// Round 6
// 91.452 us; speedup vs baseline: 1.1020x; 1.0784x over previous
//
#include <hip/hip_runtime.h>

// Problem constants (B=1 throughout)
constexpr int kH  = 1024;
constexpr int kS  = 48;
constexpr int kNH = 32;
constexpr int kDH = 32;
constexpr float kSF = 0.2f;
// Output: [48, 48*32*32*32] f32. Row x = O[x] (32x32 = 1024 f32) tiled 1536 times.
constexpr int kRepsPerRow = kS * kNH;          // 1536
constexpr int kRowF4      = kRepsPerRow * 256; // 393216 float4 per output row

typedef float f32x4 __attribute__((ext_vector_type(4)));

__device__ __forceinline__ float4 ld4(const float* p) {
    return *reinterpret_cast<const float4*>(p);
}
__device__ __forceinline__ float dot4(float4 a, float4 b) {
    return a.x * b.x + a.y * b.y + a.z * b.z + a.w * b.w;
}

// ---------------------------------------------------------------------------
// Kernel 1: projections (round-2's empirically fastest variant, unchanged).
// One wave per (g, o): lane l owns K-elements {j*256 + l*4 .. +3}, j=0..3.
// Each wave computes qp[s,o] for all 48 s, butterfly-reduces, lane 0 stores.
// ---------------------------------------------------------------------------
__global__ __launch_bounds__(256) void proj_kernel(
    const float* __restrict__ q, const float* __restrict__ k, const float* __restrict__ v,
    const float* __restrict__ Wq, const float* __restrict__ bq,
    const float* __restrict__ Wk, const float* __restrict__ bk,
    const float* __restrict__ Wv, const float* __restrict__ bv,
    float* __restrict__ ws)
{
    const int wid  = blockIdx.x * 4 + (threadIdx.x >> 6); // 0..3071
    const int lane = threadIdx.x & 63;
    const int g = wid >> 10;     // 0=q,1=k,2=v
    const int o = wid & 1023;

    const float *X, *W, *Bv;
    if (g == 0)      { X = q; W = Wq; Bv = bq; }
    else if (g == 1) { X = k; W = Wk; Bv = bk; }
    else             { X = v; W = Wv; Bv = bv; }
    float* OUT = ws + g * (kS * kH);

    const float* wr = W + o * kH + lane * 4;
    const float4 w0 = ld4(wr);
    const float4 w1 = ld4(wr + 256);
    const float4 w2 = ld4(wr + 512);
    const float4 w3 = ld4(wr + 768);

    float acc[kS];
#pragma unroll
    for (int s = 0; s < kS; ++s) {
        const float* xr = X + s * kH + lane * 4;
        float4 x0 = ld4(xr);
        float4 x1 = ld4(xr + 256);
        float4 x2 = ld4(xr + 512);
        float4 x3 = ld4(xr + 768);
        acc[s] = dot4(x0, w0) + dot4(x1, w1) + dot4(x2, w2) + dot4(x3, w3);
    }
#pragma unroll
    for (int s = 0; s < kS; ++s) {
        float a = acc[s];
        a += __shfl_xor(a, 1);
        a += __shfl_xor(a, 2);
        a += __shfl_xor(a, 4);
        a += __shfl_xor(a, 8);
        a += __shfl_xor(a, 16);
        a += __shfl_xor(a, 32);
        acc[s] = a;
    }
    if (lane == 0) {
        const float bo = Bv[o];
#pragma unroll
        for (int s = 0; s < kS; ++s) OUT[s * kH + o] = acc[s] + bo;
    }
}

// ---------------------------------------------------------------------------
// Kernel 2: per-s attention core (unchanged). One block per s.
//   _sq[n]   = (1/1024) * sum_d qp[s, n*32+d]^2
//   _sk[d,e] = (1/1024) * sum_n kp[s, n*32+d] * qp[s, n*32+e]
//   p[b,c]   = softmax_c( SF * |_sk[c,b] - _sq[b]| )       (stored transposed)
//   O[s,b,d] = sum_c p[b,c] * vp[s, c*32+d]
// ---------------------------------------------------------------------------
__global__ __launch_bounds__(256) void attn_kernel(
    const float* __restrict__ ws, float* __restrict__ O)
{
    const int s = blockIdx.x;
    const int t = threadIdx.x;

    __shared__ float qrow[kH];
    __shared__ float krow[kH];
    __shared__ float vrow[kH];
    __shared__ float sq[kNH];
    __shared__ float sk[kDH][kDH];  // sk[d][e]
    __shared__ float pT[kNH][kNH];  // pT[c][b] = p[b][c]

    const float* qp = ws;
    const float* kp = ws + kS * kH;
    const float* vp = ws + 2 * kS * kH;

    reinterpret_cast<float4*>(qrow)[t] = ld4(qp + s * kH + t * 4);
    reinterpret_cast<float4*>(krow)[t] = ld4(kp + s * kH + t * 4);
    reinterpret_cast<float4*>(vrow)[t] = ld4(vp + s * kH + t * 4);
    __syncthreads();

    if (t < kNH) {
        float a = 0.f;
#pragma unroll
        for (int d = 0; d < kDH; ++d) {
            float x = qrow[t * kDH + d];
            a += x * x;
        }
        sq[t] = a * (1.0f / 1024.0f);
    }
    {
        const int d = t >> 3;
        const int eq = t & 7;
        float4 a = {0.f, 0.f, 0.f, 0.f};
#pragma unroll
        for (int n = 0; n < kNH; ++n) {
            const float kv = krow[n * kDH + d];
            const float4 qv = reinterpret_cast<const float4*>(qrow)[n * 8 + eq];
            a.x += kv * qv.x; a.y += kv * qv.y; a.z += kv * qv.z; a.w += kv * qv.w;
        }
        const float sc = 1.0f / 1024.0f;
        a.x *= sc; a.y *= sc; a.z *= sc; a.w *= sc;
        *reinterpret_cast<float4*>(&sk[d][eq * 4]) = a;
    }
    __syncthreads();

    {
        const int b = t >> 3;
        const int c0 = (t & 7) * 4;
        const float s0 = sq[b];
        float v0 = kSF * fabsf(sk[c0 + 0][b] - s0);
        float v1 = kSF * fabsf(sk[c0 + 1][b] - s0);
        float v2 = kSF * fabsf(sk[c0 + 2][b] - s0);
        float v3 = kSF * fabsf(sk[c0 + 3][b] - s0);
        float m = fmaxf(fmaxf(v0, v1), fmaxf(v2, v3));
        m = fmaxf(m, __shfl_xor(m, 1));
        m = fmaxf(m, __shfl_xor(m, 2));
        m = fmaxf(m, __shfl_xor(m, 4));
        float e0 = __expf(v0 - m);
        float e1 = __expf(v1 - m);
        float e2 = __expf(v2 - m);
        float e3 = __expf(v3 - m);
        float sum = e0 + e1 + e2 + e3;
        sum += __shfl_xor(sum, 1);
        sum += __shfl_xor(sum, 2);
        sum += __shfl_xor(sum, 4);
        const float inv = 1.0f / sum;
        pT[c0 + 0][b] = e0 * inv;
        pT[c0 + 1][b] = e1 * inv;
        pT[c0 + 2][b] = e2 * inv;
        pT[c0 + 3][b] = e3 * inv;
    }
    __syncthreads();

    {
        const int b = t >> 3;
        const int dq = t & 7;
        float4 acc = {0.f, 0.f, 0.f, 0.f};
#pragma unroll
        for (int c = 0; c < kNH; ++c) {
            const float pv = pT[c][b];
            const float4 vv = reinterpret_cast<const float4*>(vrow)[c * 8 + dq];
            acc.x += pv * vv.x; acc.y += pv * vv.y; acc.z += pv * vv.z; acc.w += pv * vv.w;
        }
        reinterpret_cast<float4*>(O + s * kH + b * kDH)[dq] = acc;
    }
}

// ---------------------------------------------------------------------------
// Kernel 3: broadcast, CONTIGUOUS-PER-WAVE store walk (the one change).
// 4608 blocks = 48 rows x 96 rep-groups of 16; wave w owns reps rb*16+w*4..+3.
// Each lane preloads its 4 float4s of O[x] (o0..o3 = the four 1KB quarters),
// then the wave writes one contiguous 16KB span: rep-major, quarter-minor —
// every store instruction lands the wave on the next consecutive 1KB, exactly
// like fillBuffer's sweep (vs the old 4KB-strided walk from one wave).
// ---------------------------------------------------------------------------
__global__ __launch_bounds__(256) void bcast_kernel(
    const float* __restrict__ O, float* __restrict__ out)
{
    const int x  = blockIdx.x / 96;   // output row
    const int rb = blockIdx.x % 96;   // rep-group of 16
    const int w  = (threadIdx.x >> 6);// wave 0..3
    const int l  = threadIdx.x & 63;

    const f32x4* Orow = reinterpret_cast<const f32x4*>(O + x * kH);
    const f32x4 o0 = Orow[0 * 64 + l];
    const f32x4 o1 = Orow[1 * 64 + l];
    const f32x4 o2 = Orow[2 * 64 + l];
    const f32x4 o3 = Orow[3 * 64 + l];

    f32x4* base = reinterpret_cast<f32x4*>(out)
                + (size_t)x * kRowF4 + (size_t)(rb * 16 + w * 4) * 256 + l;
#pragma unroll
    for (int rep = 0; rep < 4; ++rep) {
        f32x4* p = base + rep * 256;
        __builtin_nontemporal_store(o0, p);
        __builtin_nontemporal_store(o1, p + 64);
        __builtin_nontemporal_store(o2, p + 128);
        __builtin_nontemporal_store(o3, p + 192);
    }
}

extern "C" void kernel_launch(void* const* d_in, const int* in_sizes, int n_in,
                              void* d_out, int out_size, void* d_ws, size_t ws_size,
                              hipStream_t stream)
{
    (void)in_sizes; (void)n_in; (void)out_size; (void)ws_size;
    const float* q  = (const float*)d_in[0];
    const float* k  = (const float*)d_in[1];
    const float* v  = (const float*)d_in[2];
    const float* Wq = (const float*)d_in[3];
    const float* bq = (const float*)d_in[4];
    const float* Wk = (const float*)d_in[5];
    const float* bk = (const float*)d_in[6];
    const float* Wv = (const float*)d_in[7];
    const float* bv = (const float*)d_in[8];

    float* ws  = (float*)d_ws;                 // qp | kp | vp | O
    float* O   = ws + 3 * kS * kH;
    float* out = (float*)d_out;

    proj_kernel<<<768, 256, 0, stream>>>(q, k, v, Wq, bq, Wk, bk, Wv, bv, ws);
    attn_kernel<<<kS, 256, 0, stream>>>(ws, O);
    bcast_kernel<<<kS * 96, 256, 0, stream>>>(O, out);
}

// Round 7
// 87.182 us; speedup vs baseline: 1.1560x; 1.0490x over previous
//
#include <hip/hip_runtime.h>

// Problem constants (B=1 throughout)
constexpr int kH  = 1024;
constexpr int kS  = 48;
constexpr int kNH = 32;
constexpr int kDH = 32;
constexpr float kSF = 0.2f;
// Output: [48, 48*32*32*32] f32. Row x = O[x] (32x32 = 1024 f32) tiled 1536 times.
constexpr int kRepsPerRow = kS * kNH;          // 1536
constexpr int kRowF4      = kRepsPerRow * 256; // 393216 float4 per output row

typedef float f32x4 __attribute__((ext_vector_type(4)));

__device__ __forceinline__ float4 ld4(const float* p) {
    return *reinterpret_cast<const float4*>(p);
}
__device__ __forceinline__ float dot4(float4 a, float4 b) {
    return a.x * b.x + a.y * b.y + a.z * b.z + a.w * b.w;
}

// ---------------------------------------------------------------------------
// Kernel 1: projections (round-2's empirically fastest variant, unchanged).
// One wave per (g, o): lane l owns K-elements {j*256 + l*4 .. +3}, j=0..3.
// Each wave computes qp[s,o] for all 48 s, butterfly-reduces, lane 0 stores.
// ---------------------------------------------------------------------------
__global__ __launch_bounds__(256) void proj_kernel(
    const float* __restrict__ q, const float* __restrict__ k, const float* __restrict__ v,
    const float* __restrict__ Wq, const float* __restrict__ bq,
    const float* __restrict__ Wk, const float* __restrict__ bk,
    const float* __restrict__ Wv, const float* __restrict__ bv,
    float* __restrict__ ws)
{
    const int wid  = blockIdx.x * 4 + (threadIdx.x >> 6); // 0..3071
    const int lane = threadIdx.x & 63;
    const int g = wid >> 10;     // 0=q,1=k,2=v
    const int o = wid & 1023;

    const float *X, *W, *Bv;
    if (g == 0)      { X = q; W = Wq; Bv = bq; }
    else if (g == 1) { X = k; W = Wk; Bv = bk; }
    else             { X = v; W = Wv; Bv = bv; }
    float* OUT = ws + g * (kS * kH);

    const float* wr = W + o * kH + lane * 4;
    const float4 w0 = ld4(wr);
    const float4 w1 = ld4(wr + 256);
    const float4 w2 = ld4(wr + 512);
    const float4 w3 = ld4(wr + 768);

    float acc[kS];
#pragma unroll
    for (int s = 0; s < kS; ++s) {
        const float* xr = X + s * kH + lane * 4;
        float4 x0 = ld4(xr);
        float4 x1 = ld4(xr + 256);
        float4 x2 = ld4(xr + 512);
        float4 x3 = ld4(xr + 768);
        acc[s] = dot4(x0, w0) + dot4(x1, w1) + dot4(x2, w2) + dot4(x3, w3);
    }
#pragma unroll
    for (int s = 0; s < kS; ++s) {
        float a = acc[s];
        a += __shfl_xor(a, 1);
        a += __shfl_xor(a, 2);
        a += __shfl_xor(a, 4);
        a += __shfl_xor(a, 8);
        a += __shfl_xor(a, 16);
        a += __shfl_xor(a, 32);
        acc[s] = a;
    }
    if (lane == 0) {
        const float bo = Bv[o];
#pragma unroll
        for (int s = 0; s < kS; ++s) OUT[s * kH + o] = acc[s] + bo;
    }
}

// ---------------------------------------------------------------------------
// Kernel 2: fused attn + broadcast. 4608 blocks = 48 rows x 96 rep-groups.
// Each block recomputes the 32x32 attn core for its row (622 MFLOP aggregate
// ~4 us chip-wide, hidden under the store stream), then writes 16 reps with
// the contiguous-per-wave NT walk (wave w: reps rb*16+w*4..+3, 16KB span).
// O is staged in qrow's LDS (reused after _sk phase) — ~20.5 KB LDS/block.
//   _sq[n]   = (1/1024) * sum_d qp[x, n*32+d]^2
//   _sk[d,e] = (1/1024) * sum_n kp[x, n*32+d] * qp[x, n*32+e]
//   p[b,c]   = softmax_c( SF * |_sk[c,b] - _sq[b]| )
//   O[b,d]   = sum_c p[b,c] * vp[x, c*32+d]
// ---------------------------------------------------------------------------
__global__ __launch_bounds__(256) void fused_kernel(
    const float* __restrict__ ws, float* __restrict__ out)
{
    const int x  = blockIdx.x / 96;   // output row 0..47
    const int rb = blockIdx.x % 96;   // rep-group of 16
    const int t  = threadIdx.x;

    __shared__ float qrow[kH];        // qp row, later reused as O
    __shared__ float krow[kH];
    __shared__ float vrow[kH];
    __shared__ float sq[kNH];
    __shared__ float sk[kDH][kDH];    // sk[d][e]
    __shared__ float pT[kNH][kNH];    // pT[c][b] = p[b][c]

    const float* qp = ws;
    const float* kp = ws + kS * kH;
    const float* vp = ws + 2 * kS * kH;

    reinterpret_cast<float4*>(qrow)[t] = ld4(qp + x * kH + t * 4);
    reinterpret_cast<float4*>(krow)[t] = ld4(kp + x * kH + t * 4);
    reinterpret_cast<float4*>(vrow)[t] = ld4(vp + x * kH + t * 4);
    __syncthreads();

    if (t < kNH) {
        float a = 0.f;
#pragma unroll
        for (int d = 0; d < kDH; ++d) {
            float xq = qrow[t * kDH + d];
            a += xq * xq;
        }
        sq[t] = a * (1.0f / 1024.0f);
    }
    {
        // _sk: thread t -> d = t>>3, e-quad = t&7
        const int d = t >> 3;
        const int eq = t & 7;
        float4 a = {0.f, 0.f, 0.f, 0.f};
#pragma unroll
        for (int n = 0; n < kNH; ++n) {
            const float kv = krow[n * kDH + d];
            const float4 qv = reinterpret_cast<const float4*>(qrow)[n * 8 + eq];
            a.x += kv * qv.x; a.y += kv * qv.y; a.z += kv * qv.z; a.w += kv * qv.w;
        }
        const float sc = 1.0f / 1024.0f;
        a.x *= sc; a.y *= sc; a.z *= sc; a.w *= sc;
        *reinterpret_cast<float4*>(&sk[d][eq * 4]) = a;
    }
    __syncthreads();

    {
        // softmax over c for each b: thread t -> b = t>>3, c-quad = t&7
        const int b = t >> 3;
        const int c0 = (t & 7) * 4;
        const float s0 = sq[b];
        float v0 = kSF * fabsf(sk[c0 + 0][b] - s0);
        float v1 = kSF * fabsf(sk[c0 + 1][b] - s0);
        float v2 = kSF * fabsf(sk[c0 + 2][b] - s0);
        float v3 = kSF * fabsf(sk[c0 + 3][b] - s0);
        float m = fmaxf(fmaxf(v0, v1), fmaxf(v2, v3));
        m = fmaxf(m, __shfl_xor(m, 1));
        m = fmaxf(m, __shfl_xor(m, 2));
        m = fmaxf(m, __shfl_xor(m, 4));
        float e0 = __expf(v0 - m);
        float e1 = __expf(v1 - m);
        float e2 = __expf(v2 - m);
        float e3 = __expf(v3 - m);
        float sum = e0 + e1 + e2 + e3;
        sum += __shfl_xor(sum, 1);
        sum += __shfl_xor(sum, 2);
        sum += __shfl_xor(sum, 4);
        const float inv = 1.0f / sum;
        pT[c0 + 0][b] = e0 * inv;
        pT[c0 + 1][b] = e1 * inv;
        pT[c0 + 2][b] = e2 * inv;
        pT[c0 + 3][b] = e3 * inv;
    }
    __syncthreads();   // also: qrow no longer read past here -> reuse as O

    {
        // O[b][d]: thread t -> b = t>>3, d-quad = t&7  => float4 slot = t
        const int b = t >> 3;
        const int dq = t & 7;
        float4 acc = {0.f, 0.f, 0.f, 0.f};
#pragma unroll
        for (int c = 0; c < kNH; ++c) {
            const float pv = pT[c][b];
            const float4 vv = reinterpret_cast<const float4*>(vrow)[c * 8 + dq];
            acc.x += pv * vv.x; acc.y += pv * vv.y; acc.z += pv * vv.z; acc.w += pv * vv.w;
        }
        reinterpret_cast<float4*>(qrow)[t] = acc;   // (b*8+dq) == t
    }
    __syncthreads();

    // broadcast: wave w writes reps rb*16 + w*4 .. +3 as one 16KB span
    {
        const int w = t >> 6;
        const int l = t & 63;
        const f32x4* OshF4 = reinterpret_cast<const f32x4*>(qrow);
        const f32x4 o0 = OshF4[0 * 64 + l];
        const f32x4 o1 = OshF4[1 * 64 + l];
        const f32x4 o2 = OshF4[2 * 64 + l];
        const f32x4 o3 = OshF4[3 * 64 + l];

        f32x4* base = reinterpret_cast<f32x4*>(out)
                    + (size_t)x * kRowF4 + (size_t)(rb * 16 + w * 4) * 256 + l;
#pragma unroll
        for (int rep = 0; rep < 4; ++rep) {
            f32x4* p = base + rep * 256;
            __builtin_nontemporal_store(o0, p);
            __builtin_nontemporal_store(o1, p + 64);
            __builtin_nontemporal_store(o2, p + 128);
            __builtin_nontemporal_store(o3, p + 192);
        }
    }
}

extern "C" void kernel_launch(void* const* d_in, const int* in_sizes, int n_in,
                              void* d_out, int out_size, void* d_ws, size_t ws_size,
                              hipStream_t stream)
{
    (void)in_sizes; (void)n_in; (void)out_size; (void)ws_size;
    const float* q  = (const float*)d_in[0];
    const float* k  = (const float*)d_in[1];
    const float* v  = (const float*)d_in[2];
    const float* Wq = (const float*)d_in[3];
    const float* bq = (const float*)d_in[4];
    const float* Wk = (const float*)d_in[5];
    const float* bk = (const float*)d_in[6];
    const float* Wv = (const float*)d_in[7];
    const float* bv = (const float*)d_in[8];

    float* ws  = (float*)d_ws;                 // qp | kp | vp
    float* out = (float*)d_out;

    proj_kernel<<<768, 256, 0, stream>>>(q, k, v, Wq, bq, Wk, bk, Wv, bv, ws);
    fused_kernel<<<kS * 96, 256, 0, stream>>>(ws, out);
}